// Round 10
// baseline (183.754 us; speedup 1.0000x reference)
//
#include <hip/hip_runtime.h>
#include <math.h>

typedef unsigned short ushort_t;
typedef __attribute__((ext_vector_type(8))) short short8v;
typedef __attribute__((ext_vector_type(4))) float float4v;

#define BB 2
#define NN 2048
#define HH 16
#define DHH 64
#define DIMM 1024
#define QKV3 3072
#define INNERR 1024
// 0.125 * log2(e): fold attention scale + base-2 exp into Q
#define QSCALE 0.1803368801111244f

__device__ __forceinline__ ushort_t f2bf(float f) {
    unsigned u = __float_as_uint(f);
    u += 0x7fffu + ((u >> 16) & 1u);  // round to nearest even
    return (ushort_t)(u >> 16);
}
__device__ __forceinline__ float bf2f(unsigned h) {
    return __uint_as_float(h << 16);
}
__device__ __forceinline__ unsigned pk_bf16(float a, float b) {
#if __has_builtin(__builtin_amdgcn_cvt_pk_bf16_f32)
    typedef __attribute__((ext_vector_type(2))) __bf16 bf16x2;
    bf16x2 r = __builtin_amdgcn_cvt_pk_bf16_f32(a, b);
    return __builtin_bit_cast(unsigned, r);
#else
    return (unsigned)f2bf(a) | ((unsigned)f2bf(b) << 16);
#endif
}
// bare v_exp_f32 -- OCML exp2f carries denorm/overflow guards we don't need
__device__ __forceinline__ float fast_exp2(float x) {
#if __has_builtin(__builtin_amdgcn_exp2f)
    return __builtin_amdgcn_exp2f(x);
#else
    return exp2f(x);
#endif
}
__device__ __forceinline__ float fast_rcp(float x) {
#if __has_builtin(__builtin_amdgcn_rcpf)
    return __builtin_amdgcn_rcpf(x);
#else
    return 1.0f / x;
#endif
}
__device__ __forceinline__ void gl2lds16(const void* g, void* l) {
    __builtin_amdgcn_global_load_lds(
        (const __attribute__((address_space(1))) unsigned int*)g,
        (__attribute__((address_space(3))) unsigned int*)l, 16, 0, 0);
}

// R9: conv now converts ONLY the weights (wqkv 3072 blks + wout 1024 blks);
// x is consumed fp32 directly by gemm1 (in-kernel cvt) -- kills 8 MB write +
// 8 MB read + half of conv's dispatch.
__global__ __launch_bounds__(256) void conv_fused(const float* __restrict__ wqkv,
                                                  const float* __restrict__ wout,
                                                  ushort_t* __restrict__ wqkvo,
                                                  ushort_t* __restrict__ wouto) {
    int blk = blockIdx.x;
    const float* in; ushort_t* out; int i;
    if (blk < 3072) { in = wqkv; out = wqkvo; i = blk * 256 + threadIdx.x; }
    else            { in = wout; out = wouto; i = (blk - 3072) * 256 + threadIdx.x; }
    float4 v = ((const float4*)in)[i];
    ushort4 o;
    o.x = f2bf(v.x); o.y = f2bf(v.y); o.z = f2bf(v.z); o.w = f2bf(v.w);
    ((ushort4*)out)[i] = o;
}

// ---------------------------------------------------------------------------
// GEMM1 (R9): C[m,n] = sum_k A[m,k]*B[n,k] (NT), A read DIRECTLY as fp32
// (x), converted to bf16 at fragment-read time via cvt_pk_bf16_f32 (RNE --
// identical numerics to the old conv pre-pass). 128x128 tile, BK=32,
// 4 waves 2x2 (64x64 per wave), 16 MFMA / (8 A-reads-as-fp32 + 4 B-reads)
// per K-step. A staged fp32 via gl2lds (rows = 32 floats = 8 chunks, XOR
// (c&7)^(row&7) -- flash-proven conflict-free); B staged bf16 with the
// (row>>1)&3 swizzle. LDS 48 KB -> 3 blocks/CU (grid 24x32 = 768 = 3/CU).
// 6 gl2lds/thread, vmcnt(6)-carrying barrier. ROT epilogues unchanged.
__global__ __launch_bounds__(256, 3) void gemm1_rot(const float* __restrict__ Ax,
                                                    const ushort_t* __restrict__ Bm,
                                                    const float* __restrict__ rot,
                                                    ushort_t* __restrict__ Vt,
                                                    ushort_t* __restrict__ Cout, int K) {
    __shared__ float    Asf[2][128 * 32];  // 32 KB (fp32 A-tile)
    __shared__ ushort_t Bs[2][128 * 32];   // 16 KB
    const int t = threadIdx.x;
    const int lane = t & 63;
    const int w = t >> 6;
    const int wr = w >> 1;    // wave row 0..1 (64 rows each)
    const int wc = w & 1;     // wave col 0..1 (64 cols each)
    const int quad = lane >> 4;
    const int l15 = lane & 15;
    const int m0 = blockIdx.y * 128;
    const int n0 = blockIdx.x * 128;

    float4v acc[4][4];
#pragma unroll
    for (int i = 0; i < 4; ++i)
#pragma unroll
        for (int j = 0; j < 4; ++j) acc[i][j] = (float4v)0.0f;

    // staging coords: A = 1024 fp32 chunks (128 rows x 8 chunks of 4 floats),
    // B = 512 bf16 chunks (128 rows x 4 chunks of 8 bf16). 6 per thread.
    int row_[6], lcv[6], dst[6];
#pragma unroll
    for (int u = 0; u < 6; ++u) {
        int c = u * 256 + t;
        if (u < 4) {                    // A (fp32)
            int row = c >> 3;
            row_[u] = row;
            lcv[u] = (c & 7) ^ (row & 7);
            dst[u] = c * 4;             // float units
        } else {                        // B (bf16)
            int cb = c - 1024;
            int row = cb >> 2;
            row_[u] = row;
            lcv[u] = (cb & 3) ^ ((row >> 1) & 3);
            dst[u] = cb * 8;            // ushort units
        }
    }
    // prologue: stage slab 0 into buffer 0
#pragma unroll
    for (int u = 0; u < 6; ++u) {
        if (u < 4) gl2lds16(&Ax[(size_t)(m0 + row_[u]) * K + lcv[u] * 4], &Asf[0][dst[u]]);
        else       gl2lds16(&Bm[(size_t)(n0 + row_[u]) * K + lcv[u] * 8], &Bs[0][dst[u]]);
    }
    const int NIT = K >> 5;
    for (int it = 0; it < NIT; ++it) {
        const int cur = it & 1;
        if (it + 1 < NIT) {
            const int nxt = cur ^ 1;
            const int kc = (it + 1) << 5;
#pragma unroll
            for (int u = 0; u < 6; ++u) {
                if (u < 4) gl2lds16(&Ax[(size_t)(m0 + row_[u]) * K + kc + lcv[u] * 4], &Asf[nxt][dst[u]]);
                else       gl2lds16(&Bm[(size_t)(n0 + row_[u]) * K + kc + lcv[u] * 8], &Bs[nxt][dst[u]]);
            }
            asm volatile("s_waitcnt vmcnt(6)\n\ts_barrier" ::: "memory");
        } else {
            asm volatile("s_waitcnt vmcnt(0)\n\ts_barrier" ::: "memory");
        }
        short8v a[4], b[4];
#pragma unroll
        for (int i = 0; i < 4; ++i) {
            int row = wr * 64 + i * 16 + l15;
            int r7 = row & 7;
            // fp32 chunks 2q, 2q+1 hold k = 8q..8q+7; slot = chunk ^ r7
            float4v raw0 = *(const float4v*)&Asf[cur][row * 32 + ((2 * quad) ^ r7) * 4];
            float4v raw1 = *(const float4v*)&Asf[cur][row * 32 + ((2 * quad + 1) ^ r7) * 4];
            uint4 u_;
            u_.x = pk_bf16(raw0[0], raw0[1]); u_.y = pk_bf16(raw0[2], raw0[3]);
            u_.z = pk_bf16(raw1[0], raw1[1]); u_.w = pk_bf16(raw1[2], raw1[3]);
            a[i] = __builtin_bit_cast(short8v, u_);
        }
#pragma unroll
        for (int j = 0; j < 4; ++j) {
            int row = wc * 64 + j * 16 + l15;
            int pc = quad ^ ((row >> 1) & 3);
            b[j] = *(const short8v*)&Bs[cur][row * 32 + pc * 8];
        }
#pragma unroll
        for (int i = 0; i < 4; ++i)
#pragma unroll
            for (int j = 0; j < 4; ++j)
                acc[i][j] = __builtin_amdgcn_mfma_f32_16x16x32_bf16(a[i], b[j], acc[i][j], 0, 0, 0);
        // WAR: next iteration's prefetch overwrites buf cur
        asm volatile("s_barrier" ::: "memory");
    }
    const int region = n0 >> 10;  // 0=q, 1=k, 2=v
    if (region == 2) {
        // V: write transposed + tau-permuted directly to Vt[b,h,dh,n'].
#pragma unroll
        for (int i = 0; i < 4; ++i) {
            int grow = m0 + wr * 64 + i * 16 + quad * 4;  // token, ==0 mod 4
            int bb = grow >> 11, nn_ = grow & (NN - 1);
            int tk = nn_ & 63;
            // token bits kb(1)|j2(1)|qd(2)|j1(2) -> stored tp = kb|qd|j2|j1
            int tp = (tk & 32) | ((tk & 12) << 1) | ((tk & 16) >> 2);
            int nstore = (nn_ & ~63) | tp;  // j1=0; +r appends
#pragma unroll
            for (int j = 0; j < 4; ++j) {
                int vcol = n0 + wc * 64 + j * 16 + l15 - 2048;
                int hh = vcol >> 6, dh = vcol & 63;
                uint2 st;
                st.x = pk_bf16(acc[i][j][0], acc[i][j][1]);
                st.y = pk_bf16(acc[i][j][2], acc[i][j][3]);
                *(uint2*)&Vt[((size_t)(bb * HH + hh) * DHH + dh) * NN + nstore] = st;
            }
        }
        return;
    }
    {
        float scale = (region == 0) ? QSCALE : 1.0f;
#pragma unroll
        for (int i = 0; i < 4; ++i) {
#pragma unroll
            for (int r = 0; r < 4; ++r) {
                int n = (m0 + wr * 64 + i * 16 + quad * 4 + r) & (NN - 1);
#pragma unroll
                for (int jl = 0; jl < 2; ++jl) {
                    int dh = jl * 16 + l15;
                    float plo = rot[n * DHH + dh];
                    float phi = rot[n * DHH + dh + 32];
                    float lo = acc[i][jl][r], hi = acc[i][jl + 2][r];
                    acc[i][jl][r]     = (lo * __cosf(plo) - hi * __sinf(plo)) * scale;
                    acc[i][jl + 2][r] = (hi * __cosf(phi) + lo * __sinf(phi)) * scale;
                }
            }
        }
    }
#pragma unroll
    for (int i = 0; i < 4; ++i) {
        int grow = m0 + wr * 64 + i * 16 + quad * 4;
#pragma unroll
        for (int j = 0; j < 4; ++j) {
            int gcol = n0 + wc * 64 + j * 16 + l15;
#pragma unroll
            for (int r = 0; r < 4; ++r)
                Cout[(size_t)(grow + r) * QKV3 + gcol] = f2bf(acc[i][j][r]);
        }
    }
}

// ---------------------------------------------------------------------------
// GEMM2 kernel (R9): 64x64 tile, BK=64 -> grid 16x64 = 1024 blocks =
// 4 blocks/CU (four independent barrier groups/CU -- double R8's two; the
// only lever that has moved gemm2 so far is cross-block stall hiding).
// 4 waves 2x2: wave tile 32x32, 8 MFMA from 8 ds_read per iter, NIT=16.
// 8-chunk XOR staging (flash-proven), 4 gl2lds/thread, vmcnt(4). LDS 32 KB.
template <int NOUT, bool BIAS>
__global__ __launch_bounds__(256, 4) void gemm_64(const ushort_t* __restrict__ A,
                                                  const ushort_t* __restrict__ Bm,
                                                  const float* __restrict__ bias,
                                                  float* __restrict__ Cout, int K) {
    __shared__ ushort_t As[2][64 * 64];  // 16 KB
    __shared__ ushort_t Bs[2][64 * 64];  // 16 KB
    const int t = threadIdx.x;
    const int lane = t & 63;
    const int w = t >> 6;
    const int wr = w >> 1;    // wave row: 32 rows each
    const int wc = w & 1;     // wave col: 32 cols each
    const int quad = lane >> 4;
    const int l15 = lane & 15;
    const int m0 = blockIdx.y * 64;
    const int n0 = blockIdx.x * 64;

    float4v acc[2][2];
#pragma unroll
    for (int i = 0; i < 2; ++i)
#pragma unroll
        for (int j = 0; j < 2; ++j) acc[i][j] = (float4v)0.0f;

    // staging: A 512 chunks (64 rows x 8) + B 512 chunks, 4 per thread.
    // u=0..1 -> A, u=2..3 -> B. row = c>>3, lc = (c&7)^(row&7), dst = c*8.
    int row_[4], lcv[4], dst[4];
#pragma unroll
    for (int u = 0; u < 4; ++u) {
        int c = u * 256 + t;
        int cb = (u < 2) ? c : (c - 512);
        int row = cb >> 3;
        row_[u] = row;
        lcv[u] = (cb & 7) ^ (row & 7);
        dst[u] = cb * 8;
    }
    // prologue: stage tile 0 into buffer 0
#pragma unroll
    for (int u = 0; u < 4; ++u) {
        if (u < 2) gl2lds16(&A[(size_t)(m0 + row_[u]) * K + lcv[u] * 8], &As[0][dst[u]]);
        else       gl2lds16(&Bm[(size_t)(n0 + row_[u]) * K + lcv[u] * 8], &Bs[0][dst[u]]);
    }
    const int NIT = K >> 6;
    for (int it = 0; it < NIT; ++it) {
        const int cur = it & 1;
        if (it + 1 < NIT) {
            const int nxt = cur ^ 1;
            const int kc = (it + 1) << 6;
#pragma unroll
            for (int u = 0; u < 4; ++u) {
                if (u < 2) gl2lds16(&A[(size_t)(m0 + row_[u]) * K + kc + lcv[u] * 8], &As[nxt][dst[u]]);
                else       gl2lds16(&Bm[(size_t)(n0 + row_[u]) * K + kc + lcv[u] * 8], &Bs[nxt][dst[u]]);
            }
            asm volatile("s_waitcnt vmcnt(4)\n\ts_barrier" ::: "memory");
        } else {
            asm volatile("s_waitcnt vmcnt(0)\n\ts_barrier" ::: "memory");
        }
        // frags: k-half kh -> slot (kh*4+quad)^(row&7)
        short8v a[2][2], b[2][2];
#pragma unroll
        for (int i = 0; i < 2; ++i) {
            int row = wr * 32 + i * 16 + l15;
            int r7 = row & 7;
            a[0][i] = *(const short8v*)&As[cur][row * 64 + ((quad) ^ r7) * 8];
            a[1][i] = *(const short8v*)&As[cur][row * 64 + ((4 + quad) ^ r7) * 8];
        }
#pragma unroll
        for (int j = 0; j < 2; ++j) {
            int row = wc * 32 + j * 16 + l15;
            int r7 = row & 7;
            b[0][j] = *(const short8v*)&Bs[cur][row * 64 + ((quad) ^ r7) * 8];
            b[1][j] = *(const short8v*)&Bs[cur][row * 64 + ((4 + quad) ^ r7) * 8];
        }
#pragma unroll
        for (int kh = 0; kh < 2; ++kh)
#pragma unroll
            for (int i = 0; i < 2; ++i)
#pragma unroll
                for (int j = 0; j < 2; ++j)
                    acc[i][j] = __builtin_amdgcn_mfma_f32_16x16x32_bf16(a[kh][i], b[kh][j], acc[i][j], 0, 0, 0);
        // WAR: next iteration's prefetch overwrites buf cur
        asm volatile("s_barrier" ::: "memory");
    }
#pragma unroll
    for (int i = 0; i < 2; ++i) {
        int grow = m0 + wr * 32 + i * 16 + quad * 4;
#pragma unroll
        for (int j = 0; j < 2; ++j) {
            int gcol = n0 + wc * 32 + j * 16 + l15;
            float bv = BIAS ? bias[gcol] : 0.0f;
#pragma unroll
            for (int r = 0; r < 4; ++r)
                Cout[(size_t)(grow + r) * NOUT + gcol] = acc[i][j][r] + bv;
        }
    }
}

// MFMA flash attention, no-max exp2 softmax, S^T trick (P stays in registers).
// Split-K removed (R0-R4 proved occupancy-insensitivity); l stays complete in
// registers, O divided by l in-register and written bf16 DIRECTLY to attn.
// 512 blocks = 16 qt x 32 bh, XCD swizzle, 2/CU. Converged 47-56 us across
// 7 structural variants (R0-R9, +-4 us run noise) -- parked.
__global__ __launch_bounds__(256, 2) void flash_mfma(const ushort_t* __restrict__ qkv,
                                                     const ushort_t* __restrict__ Vt,
                                                     ushort_t* __restrict__ attn) {
    __shared__ ushort_t smem[16384];  // 32 KB: Ks0|Ks1|Vts0|Vts1 (4096 each)
    const int t = threadIdx.x;
    const int lane = t & 63;
    const int w = t >> 6;
    const int quad = lane >> 4;
    const int l15 = lane & 15;
    // blk: low 3 bits = XCD residue; 4 bh per residue class keep K+V in XCD L2
    const int blk = blockIdx.x;  // 512
    const int slot = blk >> 3;   // 64: qt(4) | bhh(2)
    const int qt = slot & 15;
    const int bh = (blk & 7) * 4 + (slot >> 4);
    const int b = bh >> 4, h = bh & 15;
    const int n0 = qt * 128;     // 128-row Q tile, 32 q-rows per wave

    // Q as B-operand frags: lane l15 = q-row, k-slots = dh
    short8v bq[2][2];
#pragma unroll
    for (int g = 0; g < 2; ++g) {
        size_t qb = (size_t)(b * NN + n0 + w * 32 + g * 16 + l15) * QKV3 + h * DHH + quad * 8;
        bq[g][0] = *(const short8v*)&qkv[qb];
        bq[g][1] = *(const short8v*)&qkv[qb + 32];
    }
    float4v o_acc[2][4];
    float4v l_acc[2];
#pragma unroll
    for (int g = 0; g < 2; ++g) {
        l_acc[g] = (float4v)0.0f;
#pragma unroll
        for (int nb = 0; nb < 4; ++nb) o_acc[g][nb] = (float4v)0.0f;
    }
    const short one_bf = (short)0x3F80;
    short8v ones8 = {one_bf, one_bf, one_bf, one_bf, one_bf, one_bf, one_bf, one_bf};
    const float4v ZR = (float4v)0.0f;  // loop-invariant zero C-operand

    // staging: K 512 chunks + V 512 chunks over 256 threads (2 each)
    const int s0 = t, s1 = 256 + t;
    const int r0 = s0 >> 3, lc0 = (s0 & 7) ^ (r0 & 7);
    const int r1 = s1 >> 3, lc1 = (s1 & 7) ^ (r1 & 7);
    const int koff0 = r0 * QKV3 + lc0 * 8, koff1 = r1 * QKV3 + lc1 * 8;
    const int voff0 = r0 * NN + lc0 * 8,   voff1 = r1 * NN + lc1 * 8;
    const ushort_t* kp = qkv + (size_t)b * NN * QKV3 + INNERR + h * DHH;
    const ushort_t* vp = Vt + (size_t)(b * HH + h) * DHH * NN;

    // prologue: stage tile 0 into buffer 0
    {
        gl2lds16(kp + koff0, smem + 0 * 4096 + s0 * 8);
        gl2lds16(kp + koff1, smem + 0 * 4096 + s1 * 8);
        gl2lds16(vp + voff0, smem + 2 * 4096 + s0 * 8);
        gl2lds16(vp + voff1, smem + 2 * 4096 + s1 * 8);
    }
    for (int jt = 0; jt < 32; ++jt) {
        const int cur = jt & 1;
        if (jt < 31) {
            kp += 64 * QKV3;
            vp += 64;
            const int nxt = cur ^ 1;
            gl2lds16(kp + koff0, smem + nxt * 4096 + s0 * 8);
            gl2lds16(kp + koff1, smem + nxt * 4096 + s1 * 8);
            gl2lds16(vp + voff0, smem + (2 + nxt) * 4096 + s0 * 8);
            gl2lds16(vp + voff1, smem + (2 + nxt) * 4096 + s1 * 8);
            asm volatile("s_waitcnt vmcnt(4)\n\ts_barrier" ::: "memory");
        } else {
            asm volatile("s_waitcnt vmcnt(0)\n\ts_barrier" ::: "memory");
        }
        const ushort_t* Ksc = smem + cur * 4096;
        const ushort_t* Vtc = smem + (2 + cur) * 4096;
        // hoisted fragment reads: 8 K + 8 V ds_read_b128, shared by both g's
        short8v ak[2][4], bv[2][4];
#pragma unroll
        for (int nb = 0; nb < 4; ++nb) {
            int row = nb * 16 + l15;
            int base = row * 64;
            int r7 = row & 7;
            ak[0][nb] = *(const short8v*)&Ksc[base + ((quad) ^ r7) * 8];
            ak[1][nb] = *(const short8v*)&Ksc[base + ((4 + quad) ^ r7) * 8];
            bv[0][nb] = *(const short8v*)&Vtc[base + ((quad) ^ r7) * 8];
            bv[1][nb] = *(const short8v*)&Vtc[base + ((4 + quad) ^ r7) * 8];
        }
        __builtin_amdgcn_s_setprio(1);
        // queue both QK groups so the matrix pipe stays fed through softmax
        float4v s0v[4], s1v[4];
#pragma unroll
        for (int nb = 0; nb < 4; ++nb)
            s0v[nb] = __builtin_amdgcn_mfma_f32_16x16x32_bf16(ak[0][nb], bq[0][0], ZR, 0, 0, 0);
#pragma unroll
        for (int nb = 0; nb < 4; ++nb)
            s0v[nb] = __builtin_amdgcn_mfma_f32_16x16x32_bf16(ak[1][nb], bq[0][1], s0v[nb], 0, 0, 0);
#pragma unroll
        for (int nb = 0; nb < 4; ++nb)
            s1v[nb] = __builtin_amdgcn_mfma_f32_16x16x32_bf16(ak[0][nb], bq[1][0], ZR, 0, 0, 0);
#pragma unroll
        for (int nb = 0; nb < 4; ++nb)
            s1v[nb] = __builtin_amdgcn_mfma_f32_16x16x32_bf16(ak[1][nb], bq[1][1], s1v[nb], 0, 0, 0);
        // softmax(0) on VALU overlaps QK(1) in the MFMA pipe; PV(0) queues
        // behind; softmax(1) overlaps PV(0).
#pragma unroll
        for (int g = 0; g < 2; ++g) {
            float4v* sv = (g == 0) ? s0v : s1v;
            float p[4][4];
#pragma unroll
            for (int nb = 0; nb < 4; ++nb)
#pragma unroll
                for (int r = 0; r < 4; ++r) p[nb][r] = fast_exp2(sv[nb][r]);
            uint4 u0, u1;
            u0.x = pk_bf16(p[0][0], p[0][1]); u0.y = pk_bf16(p[0][2], p[0][3]);
            u0.z = pk_bf16(p[1][0], p[1][1]); u0.w = pk_bf16(p[1][2], p[1][3]);
            u1.x = pk_bf16(p[2][0], p[2][1]); u1.y = pk_bf16(p[2][2], p[2][3]);
            u1.z = pk_bf16(p[3][0], p[3][1]); u1.w = pk_bf16(p[3][2], p[3][3]);
            short8v ap0 = __builtin_bit_cast(short8v, u0);
            short8v ap1 = __builtin_bit_cast(short8v, u1);
            l_acc[g] = __builtin_amdgcn_mfma_f32_16x16x32_bf16(ap0, ones8, l_acc[g], 0, 0, 0);
            l_acc[g] = __builtin_amdgcn_mfma_f32_16x16x32_bf16(ap1, ones8, l_acc[g], 0, 0, 0);
#pragma unroll
            for (int nb = 0; nb < 4; ++nb) {
                o_acc[g][nb] = __builtin_amdgcn_mfma_f32_16x16x32_bf16(ap0, bv[0][nb], o_acc[g][nb], 0, 0, 0);
                o_acc[g][nb] = __builtin_amdgcn_mfma_f32_16x16x32_bf16(ap1, bv[1][nb], o_acc[g][nb], 0, 0, 0);
            }
        }
        __builtin_amdgcn_s_setprio(0);
        // WAR guard: next iteration overwrites buf cur (also guards epilogue alias)
        asm volatile("s_barrier" ::: "memory");
    }
    // fused division: l_acc C-layout row (q-row) = quad*4+r matches o_acc rows,
    // same lane -> in-register 1/l multiply, no cross-lane traffic.
    float inv[2][4];
#pragma unroll
    for (int g = 0; g < 2; ++g)
#pragma unroll
        for (int r = 0; r < 4; ++r) inv[g][r] = fast_rcp(l_acc[g][r]);
    // O epilogue: C-layout (lane=dh-within-nb, reg=q-row) -> wave-private LDS
    // transpose -> coalesced 16B stores DIRECTLY to attn[b,n,h*64+dh].
    ushort_t* osc = smem + w * (32 * 68);
#pragma unroll
    for (int g = 0; g < 2; ++g)
#pragma unroll
        for (int nb = 0; nb < 4; ++nb)
#pragma unroll
            for (int r = 0; r < 4; ++r)
                osc[(g * 16 + quad * 4 + r) * 68 + nb * 16 + l15] = f2bf(o_acc[g][nb][r] * inv[g][r]);
    __builtin_amdgcn_s_waitcnt(0);  // lgkmcnt(0): wave-private LDS ordering
    {
        int rr = lane >> 1, c0 = (lane & 1) * 32;
        size_t arow = ((size_t)(b * NN + n0 + w * 32 + rr)) * INNERR + h * DHH + c0;
#pragma unroll
        for (int u = 0; u < 4; ++u) {
            uint4 v = *(const uint4*)&osc[rr * 68 + c0 + u * 8];
            *(uint4*)&attn[arow + u * 8] = v;
        }
    }
}

extern "C" void kernel_launch(void* const* d_in, const int* in_sizes, int n_in,
                              void* d_out, int out_size, void* d_ws, size_t ws_size,
                              hipStream_t stream) {
    const float* x = (const float*)d_in[0];       // [2,2048,1024]
    const float* rot = (const float*)d_in[1];     // [2048,64]
    const float* w_qkv = (const float*)d_in[2];   // [3072,1024]
    const float* w_out = (const float*)d_in[3];   // [1024,1024]
    const float* b_out = (const float*)d_in[4];   // [1024]
    float* y = (float*)d_out;                     // [2,2048,1024] fp32

    char* ws = (char*)d_ws;
    ushort_t* qkv_bf  = (ushort_t*)(ws);               // 25,165,824 B [4096,3072] bf16 (V third unused)
    ushort_t* vt_bf   = (ushort_t*)(ws + 25165824);    //  8,388,608 B [b,h,64,2048] (tau-permuted)
    ushort_t* wout_bf = (ushort_t*)(ws + 33554432);    //  2,097,152 B
    ushort_t* wqkv_bf = (ushort_t*)(ws + 35651584);    //  6,291,456 B
    ushort_t* attn_bf = (ushort_t*)(ws + 41943040);    //  8,388,608 B

    // weights -> bf16 (x is consumed fp32 directly by gemm1 now)
    conv_fused<<<4096, 256, 0, stream>>>(w_qkv, w_out, wqkv_bf, wout_bf);
    // qkv = x @ w_qkv^T -> bf16 (q/k rotary-fused); V cols -> Vt directly
    gemm1_rot<<<dim3(24, 32), 256, 0, stream>>>(
        x, wqkv_bf, rot, vt_bf, qkv_bf, DIMM);
    // flash attention, full-K per block, fused 1/l -> attn bf16 directly
    flash_mfma<<<512, 256, 0, stream>>>(qkv_bf, vt_bf, attn_bf);
    // y = attn @ w_out^T + b_out -> fp32, 64x64 tile BK=64 (1024 blocks = 4/CU)
    gemm_64<INNERR, true><<<dim3(16, 64), 256, 0, stream>>>(
        attn_bf, wout_bf, b_out, y, INNERR);
}

// Round 11
// 174.392 us; speedup vs baseline: 1.0537x; 1.0537x over previous
//
#include <hip/hip_runtime.h>
#include <math.h>

typedef unsigned short ushort_t;
typedef __attribute__((ext_vector_type(8))) short short8v;
typedef __attribute__((ext_vector_type(4))) float float4v;

#define BB 2
#define NN 2048
#define HH 16
#define DHH 64
#define DIMM 1024
#define QKV3 3072
#define INNERR 1024
// 0.125 * log2(e): fold attention scale + base-2 exp into Q
#define QSCALE 0.1803368801111244f

__device__ __forceinline__ ushort_t f2bf(float f) {
    unsigned u = __float_as_uint(f);
    u += 0x7fffu + ((u >> 16) & 1u);  // round to nearest even
    return (ushort_t)(u >> 16);
}
__device__ __forceinline__ float bf2f(unsigned h) {
    return __uint_as_float(h << 16);
}
__device__ __forceinline__ unsigned pk_bf16(float a, float b) {
#if __has_builtin(__builtin_amdgcn_cvt_pk_bf16_f32)
    typedef __attribute__((ext_vector_type(2))) __bf16 bf16x2;
    bf16x2 r = __builtin_amdgcn_cvt_pk_bf16_f32(a, b);
    return __builtin_bit_cast(unsigned, r);
#else
    return (unsigned)f2bf(a) | ((unsigned)f2bf(b) << 16);
#endif
}
// bare v_exp_f32 -- OCML exp2f carries denorm/overflow guards we don't need
__device__ __forceinline__ float fast_exp2(float x) {
#if __has_builtin(__builtin_amdgcn_exp2f)
    return __builtin_amdgcn_exp2f(x);
#else
    return exp2f(x);
#endif
}
__device__ __forceinline__ float fast_rcp(float x) {
#if __has_builtin(__builtin_amdgcn_rcpf)
    return __builtin_amdgcn_rcpf(x);
#else
    return 1.0f / x;
#endif
}
__device__ __forceinline__ void gl2lds16(const void* g, void* l) {
    __builtin_amdgcn_global_load_lds(
        (const __attribute__((address_space(1))) unsigned int*)g,
        (__attribute__((address_space(3))) unsigned int*)l, 16, 0, 0);
}

// One kernel converts x (4096 blks), w_qkv (3072), w_out (1024) to bf16.
// R10: restored (the R9 fp32-A experiment regressed: 128B-row LDS layout
// bank-aligned every row -> 3.1M conflicts, and fp32 x doubled FETCH).
__global__ __launch_bounds__(256) void conv_fused(const float* __restrict__ x,
                                                  const float* __restrict__ wqkv,
                                                  const float* __restrict__ wout,
                                                  ushort_t* __restrict__ xo,
                                                  ushort_t* __restrict__ wqkvo,
                                                  ushort_t* __restrict__ wouto) {
    int blk = blockIdx.x;
    const float* in; ushort_t* out; int i;
    if (blk < 4096)      { in = x;    out = xo;    i = blk * 256 + threadIdx.x; }
    else if (blk < 7168) { in = wqkv; out = wqkvo; i = (blk - 4096) * 256 + threadIdx.x; }
    else                 { in = wout; out = wouto; i = (blk - 7168) * 256 + threadIdx.x; }
    float4 v = ((const float4*)in)[i];
    ushort4 o;
    o.x = f2bf(v.x); o.y = f2bf(v.y); o.z = f2bf(v.z); o.w = f2bf(v.w);
    ((ushort4*)out)[i] = o;
}

// ---------------------------------------------------------------------------
// GEMM1 kernel (R8 form + R10 XCD swizzle): C[m,n] = sum_k A[m,k]*B[n,k]
// (NT). 128x128 tile, BK=32, 16x16x32 MFMA. 4 waves 2x2, 64x64 per wave
// (16 MFMA / 8 ds_read_b128 per K-step). 768 blocks = 3/CU, launched 1D
// with a bijective XCD swizzle (768 % 8 == 0): each XCD owns 96 contiguous
// tiles = 4 m-panels x 24 n-tiles -> A-panel + B-panel reuse lands in that
// XCD's private L2 (T1, +10% when HBM-bound). Dbuf + vmcnt-carrying
// barriers, conflict-free (row>>1)&3 swizzle. ROT epilogues: rotary on q/k,
// V region written transposed+tau-permuted to Vt.
__global__ __launch_bounds__(256, 3) void gemm1_rot(const ushort_t* __restrict__ A,
                                                    const ushort_t* __restrict__ Bm,
                                                    const float* __restrict__ rot,
                                                    ushort_t* __restrict__ Vt,
                                                    ushort_t* __restrict__ Cout, int K) {
    constexpr int NCH = 4;  // (512 A + 512 B chunks) / 256 threads
    __shared__ ushort_t As[2][128 * 32];
    __shared__ ushort_t Bs[2][128 * 32];
    const int t = threadIdx.x;
    const int lane = t & 63;
    const int w = t >> 6;
    const int wr = w >> 1;    // wave row 0..1 (64 rows each)
    const int wc = w & 1;     // wave col 0..1 (64 cols each)
    const int quad = lane >> 4;
    const int l15 = lane & 15;
    // XCD swizzle: 768 blocks, 8 XCDs -> 96 contiguous tiles per XCD
    const int lid = blockIdx.x;
    const int swz = (lid & 7) * 96 + (lid >> 3);
    const int m0 = (swz / 24) * 128;
    const int n0 = (swz % 24) * 128;

    float4v acc[4][4];
#pragma unroll
    for (int i = 0; i < 4; ++i)
#pragma unroll
        for (int j = 0; j < 4; ++j) acc[i][j] = (float4v)0.0f;

    // per-thread staging coords (swizzle (row>>1)&3; conflict-free)
    int srow[NCH], slc[NCH], sdst[NCH];
    bool sisA[NCH];
#pragma unroll
    for (int u = 0; u < NCH; ++u) {
        int c = u * 256 + t;
        if (c < 512) {
            int row = c >> 2;
            sisA[u] = true; srow[u] = row; slc[u] = (c & 3) ^ ((row >> 1) & 3); sdst[u] = c * 8;
        } else {
            int cb = c - 512;
            int row = cb >> 2;
            sisA[u] = false; srow[u] = row; slc[u] = (cb & 3) ^ ((row >> 1) & 3); sdst[u] = cb * 8;
        }
    }
    // prologue: stage slab 0 into buffer 0
#pragma unroll
    for (int u = 0; u < NCH; ++u) {
        if (sisA[u]) gl2lds16(&A[(size_t)(m0 + srow[u]) * K + slc[u] * 8], &As[0][sdst[u]]);
        else         gl2lds16(&Bm[(size_t)(n0 + srow[u]) * K + slc[u] * 8], &Bs[0][sdst[u]]);
    }
    const int NIT = K >> 5;
    for (int it = 0; it < NIT; ++it) {
        const int cur = it & 1;
        if (it + 1 < NIT) {
            const int nxt = cur ^ 1;
            const int kc = (it + 1) << 5;
#pragma unroll
            for (int u = 0; u < NCH; ++u) {
                if (sisA[u]) gl2lds16(&A[(size_t)(m0 + srow[u]) * K + kc + slc[u] * 8], &As[nxt][sdst[u]]);
                else         gl2lds16(&Bm[(size_t)(n0 + srow[u]) * K + kc + slc[u] * 8], &Bs[nxt][sdst[u]]);
            }
            asm volatile("s_waitcnt vmcnt(4)\n\ts_barrier" ::: "memory");
        } else {
            asm volatile("s_waitcnt vmcnt(0)\n\ts_barrier" ::: "memory");
        }
        short8v a[4], b[4];
#pragma unroll
        for (int i = 0; i < 4; ++i) {
            int row = wr * 64 + i * 16 + l15;
            int pc = quad ^ ((row >> 1) & 3);
            a[i] = *(const short8v*)&As[cur][row * 32 + pc * 8];
        }
#pragma unroll
        for (int j = 0; j < 4; ++j) {
            int row = wc * 64 + j * 16 + l15;
            int pc = quad ^ ((row >> 1) & 3);
            b[j] = *(const short8v*)&Bs[cur][row * 32 + pc * 8];
        }
#pragma unroll
        for (int i = 0; i < 4; ++i)
#pragma unroll
            for (int j = 0; j < 4; ++j)
                acc[i][j] = __builtin_amdgcn_mfma_f32_16x16x32_bf16(a[i], b[j], acc[i][j], 0, 0, 0);
        // WAR: next iteration's prefetch overwrites buf cur
        asm volatile("s_barrier" ::: "memory");
    }
    const int region = n0 >> 10;  // 0=q, 1=k, 2=v
    if (region == 2) {
        // V: write transposed + tau-permuted directly to Vt[b,h,dh,n'].
#pragma unroll
        for (int i = 0; i < 4; ++i) {
            int grow = m0 + wr * 64 + i * 16 + quad * 4;  // token, ==0 mod 4
            int bb = grow >> 11, nn_ = grow & (NN - 1);
            int tk = nn_ & 63;
            // token bits kb(1)|j2(1)|qd(2)|j1(2) -> stored tp = kb|qd|j2|j1
            int tp = (tk & 32) | ((tk & 12) << 1) | ((tk & 16) >> 2);
            int nstore = (nn_ & ~63) | tp;  // j1=0; +r appends
#pragma unroll
            for (int j = 0; j < 4; ++j) {
                int vcol = n0 + wc * 64 + j * 16 + l15 - 2048;
                int hh = vcol >> 6, dh = vcol & 63;
                uint2 st;
                st.x = pk_bf16(acc[i][j][0], acc[i][j][1]);
                st.y = pk_bf16(acc[i][j][2], acc[i][j][3]);
                *(uint2*)&Vt[((size_t)(bb * HH + hh) * DHH + dh) * NN + nstore] = st;
            }
        }
        return;
    }
    {
        float scale = (region == 0) ? QSCALE : 1.0f;
#pragma unroll
        for (int i = 0; i < 4; ++i) {
#pragma unroll
            for (int r = 0; r < 4; ++r) {
                int n = (m0 + wr * 64 + i * 16 + quad * 4 + r) & (NN - 1);
#pragma unroll
                for (int jl = 0; jl < 2; ++jl) {
                    int dh = jl * 16 + l15;
                    float plo = rot[n * DHH + dh];
                    float phi = rot[n * DHH + dh + 32];
                    float lo = acc[i][jl][r], hi = acc[i][jl + 2][r];
                    acc[i][jl][r]     = (lo * __cosf(plo) - hi * __sinf(plo)) * scale;
                    acc[i][jl + 2][r] = (hi * __cosf(phi) + lo * __sinf(phi)) * scale;
                }
            }
        }
    }
#pragma unroll
    for (int i = 0; i < 4; ++i) {
        int grow = m0 + wr * 64 + i * 16 + quad * 4;
#pragma unroll
        for (int j = 0; j < 4; ++j) {
            int gcol = n0 + wc * 64 + j * 16 + l15;
#pragma unroll
            for (int r = 0; r < 4; ++r)
                Cout[(size_t)(grow + r) * QKV3 + gcol] = f2bf(acc[i][j][r]);
        }
    }
}

// ---------------------------------------------------------------------------
// GEMM2 kernel: 64x64 tile, BK=64 -> grid 16x64 = 1024 blocks = 4 blocks/CU
// (four independent barrier groups/CU; cross-block stall hiding is the only
// lever that has moved gemm2). 4 waves 2x2: wave tile 32x32, 8 MFMA from
// 8 ds_read per iter, NIT=16. 8-chunk XOR staging, 4 gl2lds/thread,
// vmcnt(4). LDS 32 KB. (R10 analysis: == 128x64@2/CU within noise; kept.)
template <int NOUT, bool BIAS>
__global__ __launch_bounds__(256, 4) void gemm_64(const ushort_t* __restrict__ A,
                                                  const ushort_t* __restrict__ Bm,
                                                  const float* __restrict__ bias,
                                                  float* __restrict__ Cout, int K) {
    __shared__ ushort_t As[2][64 * 64];  // 16 KB
    __shared__ ushort_t Bs[2][64 * 64];  // 16 KB
    const int t = threadIdx.x;
    const int lane = t & 63;
    const int w = t >> 6;
    const int wr = w >> 1;    // wave row: 32 rows each
    const int wc = w & 1;     // wave col: 32 cols each
    const int quad = lane >> 4;
    const int l15 = lane & 15;
    const int m0 = blockIdx.y * 64;
    const int n0 = blockIdx.x * 64;

    float4v acc[2][2];
#pragma unroll
    for (int i = 0; i < 2; ++i)
#pragma unroll
        for (int j = 0; j < 2; ++j) acc[i][j] = (float4v)0.0f;

    // staging: A 512 chunks (64 rows x 8) + B 512 chunks, 4 per thread.
    // u=0..1 -> A, u=2..3 -> B. row = c>>3, lc = (c&7)^(row&7), dst = c*8.
    int row_[4], lcv[4], dst[4];
#pragma unroll
    for (int u = 0; u < 4; ++u) {
        int c = u * 256 + t;
        int cb = (u < 2) ? c : (c - 512);
        int row = cb >> 3;
        row_[u] = row;
        lcv[u] = (cb & 7) ^ (row & 7);
        dst[u] = cb * 8;
    }
    // prologue: stage tile 0 into buffer 0
#pragma unroll
    for (int u = 0; u < 4; ++u) {
        if (u < 2) gl2lds16(&A[(size_t)(m0 + row_[u]) * K + lcv[u] * 8], &As[0][dst[u]]);
        else       gl2lds16(&Bm[(size_t)(n0 + row_[u]) * K + lcv[u] * 8], &Bs[0][dst[u]]);
    }
    const int NIT = K >> 6;
    for (int it = 0; it < NIT; ++it) {
        const int cur = it & 1;
        if (it + 1 < NIT) {
            const int nxt = cur ^ 1;
            const int kc = (it + 1) << 6;
#pragma unroll
            for (int u = 0; u < 4; ++u) {
                if (u < 2) gl2lds16(&A[(size_t)(m0 + row_[u]) * K + kc + lcv[u] * 8], &As[nxt][dst[u]]);
                else       gl2lds16(&Bm[(size_t)(n0 + row_[u]) * K + kc + lcv[u] * 8], &Bs[nxt][dst[u]]);
            }
            asm volatile("s_waitcnt vmcnt(4)\n\ts_barrier" ::: "memory");
        } else {
            asm volatile("s_waitcnt vmcnt(0)\n\ts_barrier" ::: "memory");
        }
        // frags: k-half kh -> slot (kh*4+quad)^(row&7)
        short8v a[2][2], b[2][2];
#pragma unroll
        for (int i = 0; i < 2; ++i) {
            int row = wr * 32 + i * 16 + l15;
            int r7 = row & 7;
            a[0][i] = *(const short8v*)&As[cur][row * 64 + ((quad) ^ r7) * 8];
            a[1][i] = *(const short8v*)&As[cur][row * 64 + ((4 + quad) ^ r7) * 8];
        }
#pragma unroll
        for (int j = 0; j < 2; ++j) {
            int row = wc * 32 + j * 16 + l15;
            int r7 = row & 7;
            b[0][j] = *(const short8v*)&Bs[cur][row * 64 + ((quad) ^ r7) * 8];
            b[1][j] = *(const short8v*)&Bs[cur][row * 64 + ((4 + quad) ^ r7) * 8];
        }
#pragma unroll
        for (int kh = 0; kh < 2; ++kh)
#pragma unroll
            for (int i = 0; i < 2; ++i)
#pragma unroll
                for (int j = 0; j < 2; ++j)
                    acc[i][j] = __builtin_amdgcn_mfma_f32_16x16x32_bf16(a[kh][i], b[kh][j], acc[i][j], 0, 0, 0);
        // WAR: next iteration's prefetch overwrites buf cur
        asm volatile("s_barrier" ::: "memory");
    }
#pragma unroll
    for (int i = 0; i < 2; ++i) {
        int grow = m0 + wr * 32 + i * 16 + quad * 4;
#pragma unroll
        for (int j = 0; j < 2; ++j) {
            int gcol = n0 + wc * 32 + j * 16 + l15;
            float bv = BIAS ? bias[gcol] : 0.0f;
#pragma unroll
            for (int r = 0; r < 4; ++r)
                Cout[(size_t)(grow + r) * NOUT + gcol] = acc[i][j][r] + bv;
        }
    }
}

// MFMA flash attention, no-max exp2 softmax, S^T trick (P stays in registers).
// Split-K removed (R0-R4 proved occupancy-insensitivity); l stays complete in
// registers, O divided by l in-register and written bf16 DIRECTLY to attn.
// 512 blocks = 16 qt x 32 bh, XCD swizzle, 2/CU. Converged 47-56 us across
// 7 structural variants (R0-R9, +-4 us run noise) -- parked.
__global__ __launch_bounds__(256, 2) void flash_mfma(const ushort_t* __restrict__ qkv,
                                                     const ushort_t* __restrict__ Vt,
                                                     ushort_t* __restrict__ attn) {
    __shared__ ushort_t smem[16384];  // 32 KB: Ks0|Ks1|Vts0|Vts1 (4096 each)
    const int t = threadIdx.x;
    const int lane = t & 63;
    const int w = t >> 6;
    const int quad = lane >> 4;
    const int l15 = lane & 15;
    // blk: low 3 bits = XCD residue; 4 bh per residue class keep K+V in XCD L2
    const int blk = blockIdx.x;  // 512
    const int slot = blk >> 3;   // 64: qt(4) | bhh(2)
    const int qt = slot & 15;
    const int bh = (blk & 7) * 4 + (slot >> 4);
    const int b = bh >> 4, h = bh & 15;
    const int n0 = qt * 128;     // 128-row Q tile, 32 q-rows per wave

    // Q as B-operand frags: lane l15 = q-row, k-slots = dh
    short8v bq[2][2];
#pragma unroll
    for (int g = 0; g < 2; ++g) {
        size_t qb = (size_t)(b * NN + n0 + w * 32 + g * 16 + l15) * QKV3 + h * DHH + quad * 8;
        bq[g][0] = *(const short8v*)&qkv[qb];
        bq[g][1] = *(const short8v*)&qkv[qb + 32];
    }
    float4v o_acc[2][4];
    float4v l_acc[2];
#pragma unroll
    for (int g = 0; g < 2; ++g) {
        l_acc[g] = (float4v)0.0f;
#pragma unroll
        for (int nb = 0; nb < 4; ++nb) o_acc[g][nb] = (float4v)0.0f;
    }
    const short one_bf = (short)0x3F80;
    short8v ones8 = {one_bf, one_bf, one_bf, one_bf, one_bf, one_bf, one_bf, one_bf};
    const float4v ZR = (float4v)0.0f;  // loop-invariant zero C-operand

    // staging: K 512 chunks + V 512 chunks over 256 threads (2 each)
    const int s0 = t, s1 = 256 + t;
    const int r0 = s0 >> 3, lc0 = (s0 & 7) ^ (r0 & 7);
    const int r1 = s1 >> 3, lc1 = (s1 & 7) ^ (r1 & 7);
    const int koff0 = r0 * QKV3 + lc0 * 8, koff1 = r1 * QKV3 + lc1 * 8;
    const int voff0 = r0 * NN + lc0 * 8,   voff1 = r1 * NN + lc1 * 8;
    const ushort_t* kp = qkv + (size_t)b * NN * QKV3 + INNERR + h * DHH;
    const ushort_t* vp = Vt + (size_t)(b * HH + h) * DHH * NN;

    // prologue: stage tile 0 into buffer 0
    {
        gl2lds16(kp + koff0, smem + 0 * 4096 + s0 * 8);
        gl2lds16(kp + koff1, smem + 0 * 4096 + s1 * 8);
        gl2lds16(vp + voff0, smem + 2 * 4096 + s0 * 8);
        gl2lds16(vp + voff1, smem + 2 * 4096 + s1 * 8);
    }
    for (int jt = 0; jt < 32; ++jt) {
        const int cur = jt & 1;
        if (jt < 31) {
            kp += 64 * QKV3;
            vp += 64;
            const int nxt = cur ^ 1;
            gl2lds16(kp + koff0, smem + nxt * 4096 + s0 * 8);
            gl2lds16(kp + koff1, smem + nxt * 4096 + s1 * 8);
            gl2lds16(vp + voff0, smem + (2 + nxt) * 4096 + s0 * 8);
            gl2lds16(vp + voff1, smem + (2 + nxt) * 4096 + s1 * 8);
            asm volatile("s_waitcnt vmcnt(4)\n\ts_barrier" ::: "memory");
        } else {
            asm volatile("s_waitcnt vmcnt(0)\n\ts_barrier" ::: "memory");
        }
        const ushort_t* Ksc = smem + cur * 4096;
        const ushort_t* Vtc = smem + (2 + cur) * 4096;
        // hoisted fragment reads: 8 K + 8 V ds_read_b128, shared by both g's
        short8v ak[2][4], bv[2][4];
#pragma unroll
        for (int nb = 0; nb < 4; ++nb) {
            int row = nb * 16 + l15;
            int base = row * 64;
            int r7 = row & 7;
            ak[0][nb] = *(const short8v*)&Ksc[base + ((quad) ^ r7) * 8];
            ak[1][nb] = *(const short8v*)&Ksc[base + ((4 + quad) ^ r7) * 8];
            bv[0][nb] = *(const short8v*)&Vtc[base + ((quad) ^ r7) * 8];
            bv[1][nb] = *(const short8v*)&Vtc[base + ((4 + quad) ^ r7) * 8];
        }
        __builtin_amdgcn_s_setprio(1);
        // queue both QK groups so the matrix pipe stays fed through softmax
        float4v s0v[4], s1v[4];
#pragma unroll
        for (int nb = 0; nb < 4; ++nb)
            s0v[nb] = __builtin_amdgcn_mfma_f32_16x16x32_bf16(ak[0][nb], bq[0][0], ZR, 0, 0, 0);
#pragma unroll
        for (int nb = 0; nb < 4; ++nb)
            s0v[nb] = __builtin_amdgcn_mfma_f32_16x16x32_bf16(ak[1][nb], bq[0][1], s0v[nb], 0, 0, 0);
#pragma unroll
        for (int nb = 0; nb < 4; ++nb)
            s1v[nb] = __builtin_amdgcn_mfma_f32_16x16x32_bf16(ak[0][nb], bq[1][0], ZR, 0, 0, 0);
#pragma unroll
        for (int nb = 0; nb < 4; ++nb)
            s1v[nb] = __builtin_amdgcn_mfma_f32_16x16x32_bf16(ak[1][nb], bq[1][1], s1v[nb], 0, 0, 0);
        // softmax(0) on VALU overlaps QK(1) in the MFMA pipe; PV(0) queues
        // behind; softmax(1) overlaps PV(0).
#pragma unroll
        for (int g = 0; g < 2; ++g) {
            float4v* sv = (g == 0) ? s0v : s1v;
            float p[4][4];
#pragma unroll
            for (int nb = 0; nb < 4; ++nb)
#pragma unroll
                for (int r = 0; r < 4; ++r) p[nb][r] = fast_exp2(sv[nb][r]);
            uint4 u0, u1;
            u0.x = pk_bf16(p[0][0], p[0][1]); u0.y = pk_bf16(p[0][2], p[0][3]);
            u0.z = pk_bf16(p[1][0], p[1][1]); u0.w = pk_bf16(p[1][2], p[1][3]);
            u1.x = pk_bf16(p[2][0], p[2][1]); u1.y = pk_bf16(p[2][2], p[2][3]);
            u1.z = pk_bf16(p[3][0], p[3][1]); u1.w = pk_bf16(p[3][2], p[3][3]);
            short8v ap0 = __builtin_bit_cast(short8v, u0);
            short8v ap1 = __builtin_bit_cast(short8v, u1);
            l_acc[g] = __builtin_amdgcn_mfma_f32_16x16x32_bf16(ap0, ones8, l_acc[g], 0, 0, 0);
            l_acc[g] = __builtin_amdgcn_mfma_f32_16x16x32_bf16(ap1, ones8, l_acc[g], 0, 0, 0);
#pragma unroll
            for (int nb = 0; nb < 4; ++nb) {
                o_acc[g][nb] = __builtin_amdgcn_mfma_f32_16x16x32_bf16(ap0, bv[0][nb], o_acc[g][nb], 0, 0, 0);
                o_acc[g][nb] = __builtin_amdgcn_mfma_f32_16x16x32_bf16(ap1, bv[1][nb], o_acc[g][nb], 0, 0, 0);
            }
        }
        __builtin_amdgcn_s_setprio(0);
        // WAR guard: next iteration overwrites buf cur (also guards epilogue alias)
        asm volatile("s_barrier" ::: "memory");
    }
    // fused division: l_acc C-layout row (q-row) = quad*4+r matches o_acc rows,
    // same lane -> in-register 1/l multiply, no cross-lane traffic.
    float inv[2][4];
#pragma unroll
    for (int g = 0; g < 2; ++g)
#pragma unroll
        for (int r = 0; r < 4; ++r) inv[g][r] = fast_rcp(l_acc[g][r]);
    // O epilogue: C-layout (lane=dh-within-nb, reg=q-row) -> wave-private LDS
    // transpose -> coalesced 16B stores DIRECTLY to attn[b,n,h*64+dh].
    ushort_t* osc = smem + w * (32 * 68);
#pragma unroll
    for (int g = 0; g < 2; ++g)
#pragma unroll
        for (int nb = 0; nb < 4; ++nb)
#pragma unroll
            for (int r = 0; r < 4; ++r)
                osc[(g * 16 + quad * 4 + r) * 68 + nb * 16 + l15] = f2bf(o_acc[g][nb][r] * inv[g][r]);
    __builtin_amdgcn_s_waitcnt(0);  // lgkmcnt(0): wave-private LDS ordering
    {
        int rr = lane >> 1, c0 = (lane & 1) * 32;
        size_t arow = ((size_t)(b * NN + n0 + w * 32 + rr)) * INNERR + h * DHH + c0;
#pragma unroll
        for (int u = 0; u < 4; ++u) {
            uint4 v = *(const uint4*)&osc[rr * 68 + c0 + u * 8];
            *(uint4*)&attn[arow + u * 8] = v;
        }
    }
}

extern "C" void kernel_launch(void* const* d_in, const int* in_sizes, int n_in,
                              void* d_out, int out_size, void* d_ws, size_t ws_size,
                              hipStream_t stream) {
    const float* x = (const float*)d_in[0];       // [2,2048,1024]
    const float* rot = (const float*)d_in[1];     // [2048,64]
    const float* w_qkv = (const float*)d_in[2];   // [3072,1024]
    const float* w_out = (const float*)d_in[3];   // [1024,1024]
    const float* b_out = (const float*)d_in[4];   // [1024]
    float* y = (float*)d_out;                     // [2,2048,1024] fp32

    char* ws = (char*)d_ws;
    ushort_t* qkv_bf  = (ushort_t*)(ws);               // 25,165,824 B [4096,3072] bf16 (V third unused)
    ushort_t* vt_bf   = (ushort_t*)(ws + 25165824);    //  8,388,608 B [b,h,64,2048] (tau-permuted)
    ushort_t* wout_bf = (ushort_t*)(ws + 33554432);    //  2,097,152 B
    ushort_t* wqkv_bf = (ushort_t*)(ws + 35651584);    //  6,291,456 B (dead after GEMM1)
    ushort_t* x_bf    = (ushort_t*)(ws + 41943040);    //  8,388,608 B (dead after GEMM1)
    ushort_t* attn_bf = x_bf;                          //             (aliases x_bf)

    conv_fused<<<8192, 256, 0, stream>>>(x, w_qkv, w_out, x_bf, wqkv_bf, wout_bf);
    // qkv = x @ w_qkv^T -> bf16 (q/k rotary-fused); V cols -> Vt directly
    gemm1_rot<<<768, 256, 0, stream>>>(
        x_bf, wqkv_bf, rot, vt_bf, qkv_bf, DIMM);
    // flash attention, full-K per block, fused 1/l -> attn bf16 directly
    flash_mfma<<<512, 256, 0, stream>>>(qkv_bf, vt_bf, attn_bf);
    // y = attn @ w_out^T + b_out -> fp32, 64x64 tile BK=64 (1024 blocks = 4/CU)
    gemm_64<INNERR, true><<<dim3(16, 64), 256, 0, stream>>>(
        attn_bf, wout_bf, b_out, y, INNERR);
}